// Round 6
// baseline (384.504 us; speedup 1.0000x reference)
//
#include <hip/hip_runtime.h>
#include <hip/hip_fp16.h>

// LSTM_48850958024796 — R22: port the spread-wave structure (l0's measured
// winner: R20 dense 146.8 vs R21 spread 134.5, ~9%) to lstm_l1, keeping the
// swizzle-free write-dup consumption (R18/R19 l1 win). l1 waves 0..12 own
// tiles {w, w+13}: 2 MFMA chains of depth 4 (8 MFMA/wave vs dense 16),
// quad=l16>>2 selects accA/accB, mrow=l16&3; quads 2,3 inert. 13 semi-busy
// waves vs 7 fat ones -> ~2x TLP on the latency-bound step chain.
// l0 kept at R16 structure (134.5us floor, confirmed over 4 structures).
// gemm_xg kept at R19 resident-dbuf form.
// Falsified levers (do not retry): barrier_nv (2x neutral), unroll-2 (neg),
// mega-kernel+grid.sync (724), wave specialization one-kernel (spill, 877),
// small-MB block-split (R17, 473: 2x MFMA work), dup-READ b128 in-loop (R18,
// no b128 broadcast -> 4x conflicts), l0 write-dup (R19, 141), l0 dense
// waves (R20, 147), LDS-issue reduction in l0 (R19/R20 neutral).
// Scan math (R3-proven): gates^T = W(A) @ [h|x|1]^T(B), cols gate-interleaved
// (n'=4j+gate). l0: MB=8, 2 tiles/wave, partner8 spread. l1: MB1=4, 256
// blocks, 2 tiles/wave spread (waves 0..12), write-dup cols.

typedef __attribute__((ext_vector_type(8))) short bf16x8;
typedef __attribute__((ext_vector_type(4))) float f32x4;

constexpr int Bsz = 1024, Tt = 128, IN_ = 5, H = 100, G = 400, D1 = 200;
constexpr int NP = 512;   // packed gate cols (32 tiles of 16)
constexpr int NT = 25;    // real tiles (400/16)
constexpr int MB = 8;     // batch rows per block (l0)
constexpr int MB1 = 4;    // batch rows per block (l1)
constexpr int NGRP = 4;   // row-groups per gemm_xg block
constexpr int GSTRIDE = 512;  // gemm_xg grid size

__device__ __forceinline__ float sigm(float x)   { return 1.f / (1.f + __expf(-x)); }
__device__ __forceinline__ float tanhf_(float x) { return 1.f - 2.f / (__expf(2.f * x) + 1.f); }
__device__ __forceinline__ unsigned short f2bf(float f) {
  unsigned u = __float_as_uint(f);
  u += 0x7fff + ((u >> 16) & 1);
  return (unsigned short)(u >> 16);
}
// src lane = lane & ~8 (keeps bits 0,1,2,4): MB=8 2-way spread
__device__ __forceinline__ float partner8(float v) {
  return __uint_as_float(
      (unsigned)__builtin_amdgcn_ds_swizzle((int)__float_as_uint(v), 0x17));
}

// packed col n' (0..511): j=n'>>2, gate=n'&3, src row n = gate*100+j; j>=100->0
__device__ __forceinline__ void pack_body(
    const float* wA, int KA, const float* wB, int KB, int kbo,
    const float* b1, const float* b2, int bias_k,
    unsigned short* dst, int Kg, int idx) {
  if (idx >= Kg * NP * 8) return;
  int jj = idx & 7, rest = idx >> 3;
  int np_ = rest % NP, g = rest / NP;
  int j = np_ >> 2, gate = np_ & 3;
  int k = g * 8 + jj;
  float v = 0.f;
  if (j < H) {
    int n = gate * H + j;
    if (k < KA) v = wA[n * KA + k];
    else if (KB > 0 && k >= kbo && k < kbo + KB) v = wB[n * KB + (k - kbo)];
    else if (k == bias_k) v = b1[n] + b2[n];
  }
  dst[idx] = f2bf(v);
}

__global__ void pack_all(
    const float* __restrict__ w_hh_l0f, const float* __restrict__ w_ih_l0f,
    const float* __restrict__ b_ih_l0f, const float* __restrict__ b_hh_l0f,
    const float* __restrict__ w_hh_l0b, const float* __restrict__ w_ih_l0b,
    const float* __restrict__ b_ih_l0b, const float* __restrict__ b_hh_l0b,
    const float* __restrict__ w_hh_l1f, const float* __restrict__ b_ih_l1f,
    const float* __restrict__ b_hh_l1f,
    const float* __restrict__ w_ih_l1f, const float* __restrict__ w_ih_l1b,
    const float* __restrict__ b_ih_l1b, const float* __restrict__ b_hh_l1b,
    unsigned short* __restrict__ pk0f, unsigned short* __restrict__ pk0b,
    unsigned short* __restrict__ pkhh, unsigned short* __restrict__ pkxg,
    unsigned short* __restrict__ pk1b) {
  int idx = blockIdx.x * 256 + threadIdx.x;
  switch (blockIdx.y) {
    case 0: pack_body(w_hh_l0f, 100, w_ih_l0f, 5, 100, b_ih_l0f, b_hh_l0f, 105, pk0f, 16, idx); break;
    case 1: pack_body(w_hh_l0b, 100, w_ih_l0b, 5, 100, b_ih_l0b, b_hh_l0b, 105, pk0b, 16, idx); break;
    case 2: pack_body(w_hh_l1f, 100, nullptr, 0, 0, b_ih_l1f, b_hh_l1f, -1, pkhh, 16, idx); break;
    case 3: pack_body(w_ih_l1f, 200, nullptr, 0, 0, b_ih_l1f, b_hh_l1f, 200, pkxg, 28, idx); break;
    default: pack_body(w_ih_l1b, 200, nullptr, 0, 0, b_ih_l1b, b_hh_l1b, 200, pk1b, 28, idx);
  }
}

// ------------- layer 0 scan (grid = 128 x 2 dirs, 1024 thr) -----------------
// R16 structure: 16 busy waves x 2 tiles (A=w, B=w+16), up/down lane split,
// partner8 swizzle spread; h-store tid<200, x-load tid<40 (overlap busy).
__global__ __launch_bounds__(1024, 1) void lstm_l0(
    const float* __restrict__ x,
    const unsigned short* __restrict__ pk_f, const unsigned short* __restrict__ pk_b,
    unsigned short* __restrict__ h0fT, unsigned short* __restrict__ h0bT) {
  __shared__ __align__(16) short A_s[2][16][16][8];  // [buf][kg][m16][jj], K=128

  const int tid = threadIdx.x;
  const int lane = tid & 63, w = tid >> 6;       // 16 waves
  const int q = lane >> 4, l16 = lane & 15;
  const int b0 = blockIdx.x * MB;
  const int dir = blockIdx.y;
  const unsigned short* pk = dir ? pk_b : pk_f;
  unsigned short* hT = dir ? h0bT : h0fT;

  for (int i = tid; i < 2 * 16 * 16 * 8; i += 1024) ((short*)A_s)[i] = 0;

  const int mtA = w, mtB = w + 16;
  const bool bvalid = (mtB < NT);
  bf16x8 wfA[4], wfB[4];
#pragma unroll
  for (int kt = 0; kt < 4; ++kt) {
    wfA[kt] = *(const bf16x8*)(pk + ((size_t)(kt * 4 + q) * NP + mtA * 16 + l16) * 8);
    wfB[kt] = *(const bf16x8*)(pk + ((size_t)(kt * 4 + q) * NP + mtB * 16 + l16) * 8);
  }
  float c = 0.f;
  const bool up = (l16 >= 8);
  const int mm = l16 & 7;
  const int j = (up ? mtB : mtA) * 4 + q;
  const bool valid = up ? bvalid : true;
  const int xm = tid / IN_, xe = tid - xm * IN_;              // x loader (tid<40)
  const int sm = tid / 25, sj = (tid - (tid / 25) * 25) * 4;  // h store (tid<200)
  const float* xp = x + ((size_t)(b0 + xm) * Tt + (dir ? Tt - 2 : 1)) * IN_ + xe;
  const int xstride = dir ? -IN_ : IN_;
  unsigned short* hp =
      hT + ((size_t)(dir ? Tt - 1 : 0) * Bsz + b0 + sm) * H + sj;
  const int hstride = dir ? -(Bsz * H) : (Bsz * H);
  __syncthreads();
  if (tid < 16) {  // bias-one col k=105 (kg13,jj1), both bufs
    A_s[0][13][tid][1] = (short)f2bf(1.f);
    A_s[1][13][tid][1] = (short)f2bf(1.f);
  }
  if (tid < MB * IN_) {  // x(t_first) -> buf0, direct f32 read
    int t0 = dir ? (Tt - 1) : 0;
    int k = 100 + xe;
    A_s[0][k >> 3][xm][k & 7] =
        (short)f2bf(x[((size_t)(b0 + xm) * Tt + t0) * IN_ + xe]);
  }
  __syncthreads();

  int p = 0;
  for (int step = 0; step < Tt; ++step) {
    if (step > 0 && tid < 200) {  // coalesced store of h(prev) from buf p
      uint2 hv = *(const uint2*)&A_s[p][sj >> 3][sm][sj & 7];
      *(uint2*)hp = hv;
      hp += hstride;
    }
    float xn = 0.f;
    const bool do_x = (tid < MB * IN_) && (step < Tt - 1);
    if (do_x) { xn = *xp; xp += xstride; }
    bf16x8 hfrag[4];
#pragma unroll
    for (int kt = 0; kt < 4; ++kt) hfrag[kt] = *(const bf16x8*)A_s[p][kt * 4 + q][l16];
    f32x4 accA = (f32x4){0.f, 0.f, 0.f, 0.f};
    f32x4 accB = (f32x4){0.f, 0.f, 0.f, 0.f};
#pragma unroll
    for (int kt = 0; kt < 4; ++kt)
      accA = __builtin_amdgcn_mfma_f32_16x16x32_bf16(wfA[kt], hfrag[kt], accA, 0, 0, 0);
    if (bvalid) {
#pragma unroll
      for (int kt = 0; kt < 4; ++kt)
        accB = __builtin_amdgcn_mfma_f32_16x16x32_bf16(wfB[kt], hfrag[kt], accB, 0, 0, 0);
    }
    float pb0 = partner8(accB[0]), pb1 = partner8(accB[1]);
    float pb2 = partner8(accB[2]), pb3 = partner8(accB[3]);
    float g0 = up ? pb0 : accA[0];
    float g1 = up ? pb1 : accA[1];
    float g2 = up ? pb2 : accA[2];
    float g3 = up ? pb3 : accA[3];
    float cc = sigm(g1) * c + sigm(g0) * tanhf_(g2);
    c = cc;
    float h = sigm(g3) * tanhf_(cc);
    if (valid) A_s[1 - p][j >> 3][mm][j & 7] = (short)f2bf(h);
    if (do_x) {
      int k = 100 + xe;
      A_s[1 - p][k >> 3][xm][k & 7] = (short)f2bf(xn);
    }
    __syncthreads();
    p ^= 1;
  }
  if (tid < 200) *(uint2*)hp = *(const uint2*)&A_s[p][sj >> 3][sm][sj & 7];  // final h
}

// ---- xgT[t*1024+b][400] = [h0f|h0b] @ W_ih_l1f^T + bias (fp16, interleaved) --
// 512 resident blocks x NGRP=4 row-groups, double-buffered LDS, async stage.
__global__ __launch_bounds__(1024, 1) void gemm_xg(
    const unsigned short* __restrict__ h0fT, const unsigned short* __restrict__ h0bT,
    const unsigned short* __restrict__ pkw, __half* __restrict__ xg) {
  __shared__ __align__(16) short B_s[2][28][64][8];  // K=224 aug (k=200 bias-one)
  const int tid = threadIdx.x;
  const int lane = tid & 63, w = tid >> 6;   // 16 waves
  const int q = lane >> 4, l16 = lane & 15;

  // static init: kg 25..27 both buffers (zero + bias-one at k=200, jj=0)
#pragma unroll
  for (int b = 0; b < 2; ++b)
    for (int i = tid; i < 3 * 64 * 8; i += 1024) {
      int jj = i & 7, gl = i >> 9;
      ((short*)&B_s[b][25][0][0])[i] = (short)((gl == 0 && jj == 0) ? f2bf(1.f) : 0);
    }

  const int mtA = w, mtB = w + 16;
  const bool bvalid = (mtB < NT);
  bf16x8 wfA[7], wfB[7];
#pragma unroll
  for (int kt = 0; kt < 7; ++kt) {
    wfA[kt] = *(const bf16x8*)(pkw + ((size_t)(kt * 4 + q) * NP + mtA * 16 + l16) * 8);
    wfB[kt] = *(const bf16x8*)(pkw + ((size_t)(kt * 4 + q) * NP + mtB * 16 + l16) * 8);
  }
  const int jA = mtA * 4 + q, jB = mtB * 4 + q;

  // staging tasks: idx -> (m=idx/25, j0=(idx%25)*4); tid owns idx=tid and
  // (tid<576) idx=tid+1024. 1600 tasks stage 64 rows x [h0f|h0b].
  const int t0m = tid / 25, t0j = (tid - t0m * 25) * 4;
  const int t1 = tid + 1024;
  const int t1m = t1 / 25, t1j = (t1 - t1m * 25) * 4;
  uint2 sf0, sb0, sf1, sb1;

#define XG_ISSUE(GRP)                                                  \
  {                                                                    \
    size_t base_ = (size_t)(GRP)*64 * H;                               \
    sf0 = *(const uint2*)(h0fT + base_ + t0m * H + t0j);               \
    sb0 = *(const uint2*)(h0bT + base_ + t0m * H + t0j);               \
    if (tid < 576) {                                                   \
      sf1 = *(const uint2*)(h0fT + base_ + t1m * H + t1j);             \
      sb1 = *(const uint2*)(h0bT + base_ + t1m * H + t1j);             \
    }                                                                  \
  }
#define XG_COMMIT(BUF)                                                 \
  {                                                                    \
    *(uint2*)&B_s[BUF][t0j >> 3][t0m][t0j & 7] = sf0;                  \
    int k0_ = 100 + t0j;                                               \
    *(uint2*)&B_s[BUF][k0_ >> 3][t0m][k0_ & 7] = sb0;                  \
    if (tid < 576) {                                                   \
      *(uint2*)&B_s[BUF][t1j >> 3][t1m][t1j & 7] = sf1;                \
      int k1_ = 100 + t1j;                                             \
      *(uint2*)&B_s[BUF][k1_ >> 3][t1m][k1_ & 7] = sb1;                \
    }                                                                  \
  }

  const int g0 = blockIdx.x;
  XG_ISSUE(g0);
  XG_COMMIT(0);
  __syncthreads();

  for (int i = 0; i < NGRP; ++i) {
    if (i < NGRP - 1) XG_ISSUE(g0 + GSTRIDE * (i + 1));  // issue early
    const short(*Bb)[64][8] = B_s[i & 1];
    const int r0 = (g0 + GSTRIDE * i) * 64;
#pragma unroll
    for (int rg = 0; rg < 4; ++rg) {
      f32x4 accA = (f32x4){0.f, 0.f, 0.f, 0.f};
      f32x4 accB = (f32x4){0.f, 0.f, 0.f, 0.f};
#pragma unroll
      for (int kt = 0; kt < 7; ++kt) {
        bf16x8 hf = *(const bf16x8*)Bb[kt * 4 + q][rg * 16 + l16];
        accA = __builtin_amdgcn_mfma_f32_16x16x32_bf16(wfA[kt], hf, accA, 0, 0, 0);
        if (bvalid)
          accB = __builtin_amdgcn_mfma_f32_16x16x32_bf16(wfB[kt], hf, accB, 0, 0, 0);
      }
      const size_t row = (size_t)(r0 + rg * 16 + l16);
      {
        __half2 h01 = __floats2half2_rn(accA[0], accA[1]);
        __half2 h23 = __floats2half2_rn(accA[2], accA[3]);
        uint2 st; *(__half2*)&st.x = h01; *(__half2*)&st.y = h23;
        *(uint2*)(xg + row * G + 4 * jA) = st;
      }
      if (bvalid) {
        __half2 h01 = __floats2half2_rn(accB[0], accB[1]);
        __half2 h23 = __floats2half2_rn(accB[2], accB[3]);
        uint2 st; *(__half2*)&st.x = h01; *(__half2*)&st.y = h23;
        *(uint2*)(xg + row * G + 4 * jB) = st;
      }
    }
    if (i < NGRP - 1) XG_COMMIT((i & 1) ^ 1);  // commit late, other buffer
    __syncthreads();
  }
#undef XG_ISSUE
#undef XG_COMMIT
}

// ---- layer 1: MB1=4, 256 blocks, 2 tiles/wave spread (waves 0..12) ---------
// quad=l16>>2 selects accA (tile w) / accB (tile w+13); mrow=l16&3; quads
// 2,3 inert (write-masked). Write-dup keeps all 16 cols = rows 0..3.
__global__ __launch_bounds__(1024, 1) void lstm_l1(
    const unsigned short* __restrict__ h0fT, const unsigned short* __restrict__ h0bT,
    const unsigned short* __restrict__ pk_hh, const unsigned short* __restrict__ pk1b,
    const __half* __restrict__ xg,
    const float* __restrict__ fc_w, const float* __restrict__ fc_b,
    float* __restrict__ out) {
  __shared__ __align__(16) short A_s[2][16][16][8];      // h1, K=128
  __shared__ __align__(16) short A2_s[28][16][8];        // epilogue [h0|1] K=224
  __shared__ float hf_s[MB1][H];
  __shared__ float hb_s[MB1][H];
  __shared__ float fcw_s[3 * D1];
  __shared__ float fcb_s[3];
  __shared__ float logit_s[MB1][3];

  const int tid = threadIdx.x;
  const int lane = tid & 63, w = tid >> 6;   // 16 waves
  const int q = lane >> 4, l16 = lane & 15;
  const int b0 = blockIdx.x * MB1;           // 256 blocks
  const uint2* xg2 = (const uint2*)xg;       // 100 uint2 per (t,b) row

  for (int i = tid; i < 2 * 16 * 16 * 8; i += 1024) ((short*)A_s)[i] = 0;
  for (int i = tid; i < 25 * 16 * 8; i += 1024) ((short*)A2_s)[i] = 0;  // kg 0..24
  for (int i = tid; i < 3 * 16 * 8; i += 1024) {  // A2 kg25..27 zero + bias-one
    int jj = i & 7, gl = i >> 7;
    ((short*)&A2_s[25][0][0])[i] = (short)((gl == 0 && jj == 0) ? f2bf(1.f) : 0);
  }
  for (int i = tid; i < 3 * D1; i += 1024) fcw_s[i] = fc_w[i];
  if (tid < 3) fcb_s[tid] = fc_b[tid];

  const bool busy = (w < 13);                // waves 0..12: tiles w, w+13
  const int quad = l16 >> 2, mrow = l16 & 3;
  const int mtA = w, mtB = w + 13;           // mtB<=28<32, pk zero-padded
  const bool bv = busy && (mtB < NT);        // w<12
  const int mtMine = (quad & 1) ? mtB : mtA;
  const int jme = mtMine * 4 + q;            // <=103
  const bool evalid = busy && (mtMine < NT) && (quad < 2);
  const bool ld = busy && (quad < 2);        // xg loader lanes
  bf16x8 wfA[4], wfB[4];
  if (busy) {
#pragma unroll
    for (int kt = 0; kt < 4; ++kt) {
      wfA[kt] = *(const bf16x8*)(pk_hh + ((size_t)(kt * 4 + q) * NP + mtA * 16 + l16) * 8);
      wfB[kt] = *(const bf16x8*)(pk_hh + ((size_t)(kt * 4 + q) * NP + mtB * 16 + l16) * 8);
    }
  }
  float c = 0.f;
  // per-lane own-element xg, running pointer (+102400 uint2 per t);
  // invalid jme (<=103) overruns <=32B past xg end — lands in ws, unused.
  const uint2* xgp = xg2 + (size_t)(b0 + mrow) * 100 + jme;
  uint2 xgCur = {0, 0};
  if (ld) { xgCur = *xgp; xgp += Bsz * 100; }
  __syncthreads();

  int p = 0;
  for (int t = 0; t < Tt; ++t) {
    if (busy) {
      uint2 xgNxt = xgCur;
      if (ld && t < Tt - 1) { xgNxt = *xgp; xgp += Bsz * 100; }
      bf16x8 hfrag[4];
      // [l16] read: all 16 cols hold write-time duplicates of rows 0..3.
#pragma unroll
      for (int kt = 0; kt < 4; ++kt) hfrag[kt] = *(const bf16x8*)A_s[p][kt * 4 + q][l16];
      f32x4 accA = (f32x4){0.f, 0.f, 0.f, 0.f};
      f32x4 accB = (f32x4){0.f, 0.f, 0.f, 0.f};
#pragma unroll
      for (int kt = 0; kt < 4; ++kt)
        accA = __builtin_amdgcn_mfma_f32_16x16x32_bf16(wfA[kt], hfrag[kt], accA, 0, 0, 0);
      if (bv) {
#pragma unroll
        for (int kt = 0; kt < 4; ++kt)
          accB = __builtin_amdgcn_mfma_f32_16x16x32_bf16(wfB[kt], hfrag[kt], accB, 0, 0, 0);
      }
      float2 x01 = __half22float2(*(const __half2*)&xgCur.x);
      float2 x23 = __half22float2(*(const __half2*)&xgCur.y);
      const bool useB = (quad & 1);
      float g0 = (useB ? accB[0] : accA[0]) + x01.x;
      float g1 = (useB ? accB[1] : accA[1]) + x01.y;
      float g2 = (useB ? accB[2] : accA[2]) + x23.x;
      float g3 = (useB ? accB[3] : accA[3]) + x23.y;
      float cc = sigm(g1) * c + sigm(g0) * tanhf_(g2);
      c = cc;
      float h = sigm(g3) * tanhf_(cc);
      if (evalid) {  // write-dup into all 4 mirror columns
        short hh = (short)f2bf(h);
        A_s[1 - p][jme >> 3][mrow][jme & 7] = hh;
        A_s[1 - p][jme >> 3][mrow + 4][jme & 7] = hh;
        A_s[1 - p][jme >> 3][mrow + 8][jme & 7] = hh;
        A_s[1 - p][jme >> 3][mrow + 12][jme & 7] = hh;
        if (t == Tt - 1) hf_s[mrow][jme] = h;
      }
      xgCur = xgNxt;
    }
    __syncthreads();
    p ^= 1;
  }

  // ---- layer-1 backward single step at t=T-1 (h=c=0) ----
  {
    const size_t base = ((size_t)(Tt - 1) * Bsz + b0) * H;
    if (tid < 100) {  // stage rows m=0..3 only (this block's batch)
      int m2 = tid / 25, j0 = (tid - (tid / 25) * 25) * 4;
      *(uint2*)&A2_s[j0 >> 3][m2][j0 & 7] = *(const uint2*)(h0fT + base + m2 * H + j0);
      int k = 100 + j0;
      *(uint2*)&A2_s[k >> 3][m2][k & 7] = *(const uint2*)(h0bT + base + m2 * H + j0);
    }
  }
  __syncthreads();
  if (busy) {
    f32x4 accA = (f32x4){0.f, 0.f, 0.f, 0.f};
    f32x4 accB = (f32x4){0.f, 0.f, 0.f, 0.f};
#pragma unroll
    for (int kt = 0; kt < 7; ++kt) {
      bf16x8 hf = *(const bf16x8*)A2_s[kt * 4 + q][l16 & 3];  // one-shot dup-read
      bf16x8 wa = *(const bf16x8*)(pk1b + ((size_t)(kt * 4 + q) * NP + mtA * 16 + l16) * 8);
      accA = __builtin_amdgcn_mfma_f32_16x16x32_bf16(wa, hf, accA, 0, 0, 0);
      if (bv) {
        bf16x8 wb = *(const bf16x8*)(pk1b + ((size_t)(kt * 4 + q) * NP + mtB * 16 + l16) * 8);
        accB = __builtin_amdgcn_mfma_f32_16x16x32_bf16(wb, hf, accB, 0, 0, 0);
      }
    }
    const bool useB = (quad & 1);
    float g0 = useB ? accB[0] : accA[0];
    float g2 = useB ? accB[2] : accA[2];
    float g3 = useB ? accB[3] : accA[3];
    float cc = sigm(g0) * tanhf_(g2);   // c_prev = 0
    if (evalid) hb_s[mrow][jme] = sigm(g3) * tanhf_(cc);
  }
  __syncthreads();

  // ---- FC (3x200) + softmax ----
  if (tid < MB1 * 3) {
    int mr = tid / 3, cls = tid - mr * 3;
    float s = fcb_s[cls];
    for (int jj = 0; jj < H; ++jj) s += fcw_s[cls * D1 + jj] * hf_s[mr][jj];
    for (int jj = 0; jj < H; ++jj) s += fcw_s[cls * D1 + H + jj] * hb_s[mr][jj];
    logit_s[mr][cls] = s;
  }
  __syncthreads();
  if (tid < MB1) {
    float a = logit_s[tid][0], b = logit_s[tid][1], cc = logit_s[tid][2];
    float mx = fmaxf(a, fmaxf(b, cc));
    float e0 = __expf(a - mx), e1 = __expf(b - mx), e2 = __expf(cc - mx);
    float inv = 1.f / (e0 + e1 + e2);
    out[(b0 + tid) * 3 + 0] = e0 * inv;
    out[(b0 + tid) * 3 + 1] = e1 * inv;
    out[(b0 + tid) * 3 + 2] = e2 * inv;
  }
}

extern "C" void kernel_launch(void* const* d_in, const int* in_sizes, int n_in,
                              void* d_out, int out_size, void* d_ws, size_t ws_size,
                              hipStream_t stream) {
  const float* x        = (const float*)d_in[0];
  const float* w_ih_l0f = (const float*)d_in[1];
  const float* w_hh_l0f = (const float*)d_in[2];
  const float* b_ih_l0f = (const float*)d_in[3];
  const float* b_hh_l0f = (const float*)d_in[4];
  const float* w_ih_l0b = (const float*)d_in[5];
  const float* w_hh_l0b = (const float*)d_in[6];
  const float* b_ih_l0b = (const float*)d_in[7];
  const float* b_hh_l0b = (const float*)d_in[8];
  const float* w_ih_l1f = (const float*)d_in[9];
  const float* w_hh_l1f = (const float*)d_in[10];
  const float* b_ih_l1f = (const float*)d_in[11];
  const float* b_hh_l1f = (const float*)d_in[12];
  const float* w_ih_l1b = (const float*)d_in[13];
  // d_in[14] = w_hh_l1b unused (reverse dir at t=T-1 has h=0)
  const float* b_ih_l1b = (const float*)d_in[15];
  const float* b_hh_l1b = (const float*)d_in[16];
  const float* fc_w     = (const float*)d_in[17];
  const float* fc_b     = (const float*)d_in[18];

  unsigned short* h0fT = (unsigned short*)d_ws;
  unsigned short* h0bT = h0fT + (size_t)Tt * Bsz * H;
  __half* xgT          = (__half*)(h0bT + (size_t)Tt * Bsz * H);
  unsigned short* pk0f = (unsigned short*)(xgT + (size_t)Tt * Bsz * G);
  unsigned short* pk0b = pk0f + 16 * NP * 8;
  unsigned short* pkhh = pk0b + 16 * NP * 8;
  unsigned short* pkxg = pkhh + 16 * NP * 8;
  unsigned short* pk1b = pkxg + 28 * NP * 8;

  pack_all<<<dim3(448, 5), 256, 0, stream>>>(
      w_hh_l0f, w_ih_l0f, b_ih_l0f, b_hh_l0f,
      w_hh_l0b, w_ih_l0b, b_ih_l0b, b_hh_l0b,
      w_hh_l1f, b_ih_l1f, b_hh_l1f,
      w_ih_l1f, w_ih_l1b, b_ih_l1b, b_hh_l1b,
      pk0f, pk0b, pkhh, pkxg, pk1b);

  lstm_l0<<<dim3(Bsz / MB, 2), 1024, 0, stream>>>(x, pk0f, pk0b, h0fT, h0bT);
  gemm_xg<<<GSTRIDE, 1024, 0, stream>>>(h0fT, h0bT, pkxg, xgT);
  lstm_l1<<<Bsz / MB1, 1024, 0, stream>>>(h0fT, h0bT, pkhh, pk1b, xgT,
                                          fc_w, fc_b, (float*)d_out);
}

// Round 7
// 346.037 us; speedup vs baseline: 1.1112x; 1.1112x over previous
//
#include <hip/hip_runtime.h>
#include <hip/hip_fp16.h>

// LSTM_48850958024796 — R23: pure revert to R21 (measured session best,
// 354.6us). R22's spread-wave l1 regressed 112-120 -> 141.8 (total 384.5) and
// fixed the attribution: R20's dense-l0 loss was the 2-cells/lane serial
// transcendental chain, NOT wave count. For 1-cell/lane scans, dense wins.
// Final structure ledger (all A/B-measured):
//   l0 = R16 form (16 waves x 2 tiles, partner8 spread): 134.5us floor.
//       Falsified: dup-read (140), write-dup (141), dense+dedicated-IO (147),
//       512-thr split (190).
//   l1 = dense 7 waves x 4 tiles, write-dup, swizzle-free: ~112-120us.
//       Falsified: partner4 swizzle (R16 form), spread 13 waves (141.8).
//   gemm_xg = 512 resident blocks, dbuf LDS, async stage.
//   Cross-kernel: barrier_nv (2x neutral), unroll-2 (neg), mega-kernel+
//   grid.sync (724), wave-specialization (spill, 877), small-MB split (473).
// Scan math (R3-proven): gates^T = W(A) @ [h|x|1]^T(B), cols gate-interleaved
// (n'=4j+gate). l0: MB=8, 2 tiles/wave, spread via ds_swizzle(0x17).
// l1: MB1=4, 256 blocks, dense 4 tiles/wave (waves 0..6), write-dup cols.

typedef __attribute__((ext_vector_type(8))) short bf16x8;
typedef __attribute__((ext_vector_type(4))) float f32x4;

constexpr int Bsz = 1024, Tt = 128, IN_ = 5, H = 100, G = 400, D1 = 200;
constexpr int NP = 512;   // packed gate cols (32 tiles of 16)
constexpr int NT = 25;    // real tiles (400/16)
constexpr int MB = 8;     // batch rows per block (l0)
constexpr int MB1 = 4;    // batch rows per block (l1)
constexpr int NGRP = 4;   // row-groups per gemm_xg block
constexpr int GSTRIDE = 512;  // gemm_xg grid size

__device__ __forceinline__ float sigm(float x)   { return 1.f / (1.f + __expf(-x)); }
__device__ __forceinline__ float tanhf_(float x) { return 1.f - 2.f / (__expf(2.f * x) + 1.f); }
__device__ __forceinline__ unsigned short f2bf(float f) {
  unsigned u = __float_as_uint(f);
  u += 0x7fff + ((u >> 16) & 1);
  return (unsigned short)(u >> 16);
}
// src lane = lane & ~8 (keeps bits 0,1,2,4): MB=8 2-way spread
__device__ __forceinline__ float partner8(float v) {
  return __uint_as_float(
      (unsigned)__builtin_amdgcn_ds_swizzle((int)__float_as_uint(v), 0x17));
}

// packed col n' (0..511): j=n'>>2, gate=n'&3, src row n = gate*100+j; j>=100->0
__device__ __forceinline__ void pack_body(
    const float* wA, int KA, const float* wB, int KB, int kbo,
    const float* b1, const float* b2, int bias_k,
    unsigned short* dst, int Kg, int idx) {
  if (idx >= Kg * NP * 8) return;
  int jj = idx & 7, rest = idx >> 3;
  int np_ = rest % NP, g = rest / NP;
  int j = np_ >> 2, gate = np_ & 3;
  int k = g * 8 + jj;
  float v = 0.f;
  if (j < H) {
    int n = gate * H + j;
    if (k < KA) v = wA[n * KA + k];
    else if (KB > 0 && k >= kbo && k < kbo + KB) v = wB[n * KB + (k - kbo)];
    else if (k == bias_k) v = b1[n] + b2[n];
  }
  dst[idx] = f2bf(v);
}

__global__ void pack_all(
    const float* __restrict__ w_hh_l0f, const float* __restrict__ w_ih_l0f,
    const float* __restrict__ b_ih_l0f, const float* __restrict__ b_hh_l0f,
    const float* __restrict__ w_hh_l0b, const float* __restrict__ w_ih_l0b,
    const float* __restrict__ b_ih_l0b, const float* __restrict__ b_hh_l0b,
    const float* __restrict__ w_hh_l1f, const float* __restrict__ b_ih_l1f,
    const float* __restrict__ b_hh_l1f,
    const float* __restrict__ w_ih_l1f, const float* __restrict__ w_ih_l1b,
    const float* __restrict__ b_ih_l1b, const float* __restrict__ b_hh_l1b,
    unsigned short* __restrict__ pk0f, unsigned short* __restrict__ pk0b,
    unsigned short* __restrict__ pkhh, unsigned short* __restrict__ pkxg,
    unsigned short* __restrict__ pk1b) {
  int idx = blockIdx.x * 256 + threadIdx.x;
  switch (blockIdx.y) {
    case 0: pack_body(w_hh_l0f, 100, w_ih_l0f, 5, 100, b_ih_l0f, b_hh_l0f, 105, pk0f, 16, idx); break;
    case 1: pack_body(w_hh_l0b, 100, w_ih_l0b, 5, 100, b_ih_l0b, b_hh_l0b, 105, pk0b, 16, idx); break;
    case 2: pack_body(w_hh_l1f, 100, nullptr, 0, 0, b_ih_l1f, b_hh_l1f, -1, pkhh, 16, idx); break;
    case 3: pack_body(w_ih_l1f, 200, nullptr, 0, 0, b_ih_l1f, b_hh_l1f, 200, pkxg, 28, idx); break;
    default: pack_body(w_ih_l1b, 200, nullptr, 0, 0, b_ih_l1b, b_hh_l1b, 200, pk1b, 28, idx);
  }
}

// ------------- layer 0 scan (grid = 128 x 2 dirs, 1024 thr) -----------------
// R16 structure: 16 busy waves x 2 tiles (A=w, B=w+16), up/down lane split,
// partner8 swizzle spread; h-store tid<200, x-load tid<40 (overlap busy).
__global__ __launch_bounds__(1024, 1) void lstm_l0(
    const float* __restrict__ x,
    const unsigned short* __restrict__ pk_f, const unsigned short* __restrict__ pk_b,
    unsigned short* __restrict__ h0fT, unsigned short* __restrict__ h0bT) {
  __shared__ __align__(16) short A_s[2][16][16][8];  // [buf][kg][m16][jj], K=128

  const int tid = threadIdx.x;
  const int lane = tid & 63, w = tid >> 6;       // 16 waves
  const int q = lane >> 4, l16 = lane & 15;
  const int b0 = blockIdx.x * MB;
  const int dir = blockIdx.y;
  const unsigned short* pk = dir ? pk_b : pk_f;
  unsigned short* hT = dir ? h0bT : h0fT;

  for (int i = tid; i < 2 * 16 * 16 * 8; i += 1024) ((short*)A_s)[i] = 0;

  const int mtA = w, mtB = w + 16;
  const bool bvalid = (mtB < NT);
  bf16x8 wfA[4], wfB[4];
#pragma unroll
  for (int kt = 0; kt < 4; ++kt) {
    wfA[kt] = *(const bf16x8*)(pk + ((size_t)(kt * 4 + q) * NP + mtA * 16 + l16) * 8);
    wfB[kt] = *(const bf16x8*)(pk + ((size_t)(kt * 4 + q) * NP + mtB * 16 + l16) * 8);
  }
  float c = 0.f;
  const bool up = (l16 >= 8);
  const int mm = l16 & 7;
  const int j = (up ? mtB : mtA) * 4 + q;
  const bool valid = up ? bvalid : true;
  const int xm = tid / IN_, xe = tid - xm * IN_;              // x loader (tid<40)
  const int sm = tid / 25, sj = (tid - (tid / 25) * 25) * 4;  // h store (tid<200)
  const float* xp = x + ((size_t)(b0 + xm) * Tt + (dir ? Tt - 2 : 1)) * IN_ + xe;
  const int xstride = dir ? -IN_ : IN_;
  unsigned short* hp =
      hT + ((size_t)(dir ? Tt - 1 : 0) * Bsz + b0 + sm) * H + sj;
  const int hstride = dir ? -(Bsz * H) : (Bsz * H);
  __syncthreads();
  if (tid < 16) {  // bias-one col k=105 (kg13,jj1), both bufs
    A_s[0][13][tid][1] = (short)f2bf(1.f);
    A_s[1][13][tid][1] = (short)f2bf(1.f);
  }
  if (tid < MB * IN_) {  // x(t_first) -> buf0, direct f32 read
    int t0 = dir ? (Tt - 1) : 0;
    int k = 100 + xe;
    A_s[0][k >> 3][xm][k & 7] =
        (short)f2bf(x[((size_t)(b0 + xm) * Tt + t0) * IN_ + xe]);
  }
  __syncthreads();

  int p = 0;
  for (int step = 0; step < Tt; ++step) {
    if (step > 0 && tid < 200) {  // coalesced store of h(prev) from buf p
      uint2 hv = *(const uint2*)&A_s[p][sj >> 3][sm][sj & 7];
      *(uint2*)hp = hv;
      hp += hstride;
    }
    float xn = 0.f;
    const bool do_x = (tid < MB * IN_) && (step < Tt - 1);
    if (do_x) { xn = *xp; xp += xstride; }
    bf16x8 hfrag[4];
#pragma unroll
    for (int kt = 0; kt < 4; ++kt) hfrag[kt] = *(const bf16x8*)A_s[p][kt * 4 + q][l16];
    f32x4 accA = (f32x4){0.f, 0.f, 0.f, 0.f};
    f32x4 accB = (f32x4){0.f, 0.f, 0.f, 0.f};
#pragma unroll
    for (int kt = 0; kt < 4; ++kt)
      accA = __builtin_amdgcn_mfma_f32_16x16x32_bf16(wfA[kt], hfrag[kt], accA, 0, 0, 0);
    if (bvalid) {
#pragma unroll
      for (int kt = 0; kt < 4; ++kt)
        accB = __builtin_amdgcn_mfma_f32_16x16x32_bf16(wfB[kt], hfrag[kt], accB, 0, 0, 0);
    }
    float pb0 = partner8(accB[0]), pb1 = partner8(accB[1]);
    float pb2 = partner8(accB[2]), pb3 = partner8(accB[3]);
    float g0 = up ? pb0 : accA[0];
    float g1 = up ? pb1 : accA[1];
    float g2 = up ? pb2 : accA[2];
    float g3 = up ? pb3 : accA[3];
    float cc = sigm(g1) * c + sigm(g0) * tanhf_(g2);
    c = cc;
    float h = sigm(g3) * tanhf_(cc);
    if (valid) A_s[1 - p][j >> 3][mm][j & 7] = (short)f2bf(h);
    if (do_x) {
      int k = 100 + xe;
      A_s[1 - p][k >> 3][xm][k & 7] = (short)f2bf(xn);
    }
    __syncthreads();
    p ^= 1;
  }
  if (tid < 200) *(uint2*)hp = *(const uint2*)&A_s[p][sj >> 3][sm][sj & 7];  // final h
}

// ---- xgT[t*1024+b][400] = [h0f|h0b] @ W_ih_l1f^T + bias (fp16, interleaved) --
// 512 resident blocks x NGRP=4 row-groups, double-buffered LDS, async stage.
__global__ __launch_bounds__(1024, 1) void gemm_xg(
    const unsigned short* __restrict__ h0fT, const unsigned short* __restrict__ h0bT,
    const unsigned short* __restrict__ pkw, __half* __restrict__ xg) {
  __shared__ __align__(16) short B_s[2][28][64][8];  // K=224 aug (k=200 bias-one)
  const int tid = threadIdx.x;
  const int lane = tid & 63, w = tid >> 6;   // 16 waves
  const int q = lane >> 4, l16 = lane & 15;

  // static init: kg 25..27 both buffers (zero + bias-one at k=200, jj=0)
#pragma unroll
  for (int b = 0; b < 2; ++b)
    for (int i = tid; i < 3 * 64 * 8; i += 1024) {
      int jj = i & 7, gl = i >> 9;
      ((short*)&B_s[b][25][0][0])[i] = (short)((gl == 0 && jj == 0) ? f2bf(1.f) : 0);
    }

  const int mtA = w, mtB = w + 16;
  const bool bvalid = (mtB < NT);
  bf16x8 wfA[7], wfB[7];
#pragma unroll
  for (int kt = 0; kt < 7; ++kt) {
    wfA[kt] = *(const bf16x8*)(pkw + ((size_t)(kt * 4 + q) * NP + mtA * 16 + l16) * 8);
    wfB[kt] = *(const bf16x8*)(pkw + ((size_t)(kt * 4 + q) * NP + mtB * 16 + l16) * 8);
  }
  const int jA = mtA * 4 + q, jB = mtB * 4 + q;

  // staging tasks: idx -> (m=idx/25, j0=(idx%25)*4); tid owns idx=tid and
  // (tid<576) idx=tid+1024. 1600 tasks stage 64 rows x [h0f|h0b].
  const int t0m = tid / 25, t0j = (tid - t0m * 25) * 4;
  const int t1 = tid + 1024;
  const int t1m = t1 / 25, t1j = (t1 - t1m * 25) * 4;
  uint2 sf0, sb0, sf1, sb1;

#define XG_ISSUE(GRP)                                                  \
  {                                                                    \
    size_t base_ = (size_t)(GRP)*64 * H;                               \
    sf0 = *(const uint2*)(h0fT + base_ + t0m * H + t0j);               \
    sb0 = *(const uint2*)(h0bT + base_ + t0m * H + t0j);               \
    if (tid < 576) {                                                   \
      sf1 = *(const uint2*)(h0fT + base_ + t1m * H + t1j);             \
      sb1 = *(const uint2*)(h0bT + base_ + t1m * H + t1j);             \
    }                                                                  \
  }
#define XG_COMMIT(BUF)                                                 \
  {                                                                    \
    *(uint2*)&B_s[BUF][t0j >> 3][t0m][t0j & 7] = sf0;                  \
    int k0_ = 100 + t0j;                                               \
    *(uint2*)&B_s[BUF][k0_ >> 3][t0m][k0_ & 7] = sb0;                  \
    if (tid < 576) {                                                   \
      *(uint2*)&B_s[BUF][t1j >> 3][t1m][t1j & 7] = sf1;                \
      int k1_ = 100 + t1j;                                             \
      *(uint2*)&B_s[BUF][k1_ >> 3][t1m][k1_ & 7] = sb1;                \
    }                                                                  \
  }

  const int g0 = blockIdx.x;
  XG_ISSUE(g0);
  XG_COMMIT(0);
  __syncthreads();

  for (int i = 0; i < NGRP; ++i) {
    if (i < NGRP - 1) XG_ISSUE(g0 + GSTRIDE * (i + 1));  // issue early
    const short(*Bb)[64][8] = B_s[i & 1];
    const int r0 = (g0 + GSTRIDE * i) * 64;
#pragma unroll
    for (int rg = 0; rg < 4; ++rg) {
      f32x4 accA = (f32x4){0.f, 0.f, 0.f, 0.f};
      f32x4 accB = (f32x4){0.f, 0.f, 0.f, 0.f};
#pragma unroll
      for (int kt = 0; kt < 7; ++kt) {
        bf16x8 hf = *(const bf16x8*)Bb[kt * 4 + q][rg * 16 + l16];
        accA = __builtin_amdgcn_mfma_f32_16x16x32_bf16(wfA[kt], hf, accA, 0, 0, 0);
        if (bvalid)
          accB = __builtin_amdgcn_mfma_f32_16x16x32_bf16(wfB[kt], hf, accB, 0, 0, 0);
      }
      const size_t row = (size_t)(r0 + rg * 16 + l16);
      {
        __half2 h01 = __floats2half2_rn(accA[0], accA[1]);
        __half2 h23 = __floats2half2_rn(accA[2], accA[3]);
        uint2 st; *(__half2*)&st.x = h01; *(__half2*)&st.y = h23;
        *(uint2*)(xg + row * G + 4 * jA) = st;
      }
      if (bvalid) {
        __half2 h01 = __floats2half2_rn(accB[0], accB[1]);
        __half2 h23 = __floats2half2_rn(accB[2], accB[3]);
        uint2 st; *(__half2*)&st.x = h01; *(__half2*)&st.y = h23;
        *(uint2*)(xg + row * G + 4 * jB) = st;
      }
    }
    if (i < NGRP - 1) XG_COMMIT((i & 1) ^ 1);  // commit late, other buffer
    __syncthreads();
  }
#undef XG_ISSUE
#undef XG_COMMIT
}

// ---- layer 1: MB1=4, 256 blocks, dense 4 tiles/wave (waves 0..6 busy) ------
__global__ __launch_bounds__(1024, 1) void lstm_l1(
    const unsigned short* __restrict__ h0fT, const unsigned short* __restrict__ h0bT,
    const unsigned short* __restrict__ pk_hh, const unsigned short* __restrict__ pk1b,
    const __half* __restrict__ xg,
    const float* __restrict__ fc_w, const float* __restrict__ fc_b,
    float* __restrict__ out) {
  __shared__ __align__(16) short A_s[2][16][16][8];      // h1, K=128
  __shared__ __align__(16) short A2_s[28][16][8];        // epilogue [h0|1] K=224
  __shared__ float hf_s[MB1][H];
  __shared__ float hb_s[MB1][H];
  __shared__ float fcw_s[3 * D1];
  __shared__ float fcb_s[3];
  __shared__ float logit_s[MB1][3];

  const int tid = threadIdx.x;
  const int lane = tid & 63, w = tid >> 6;   // 16 waves
  const int q = lane >> 4, l16 = lane & 15;
  const int b0 = blockIdx.x * MB1;           // 256 blocks
  const uint2* xg2 = (const uint2*)xg;       // 100 uint2 per (t,b) row

  for (int i = tid; i < 2 * 16 * 16 * 8; i += 1024) ((short*)A_s)[i] = 0;
  for (int i = tid; i < 25 * 16 * 8; i += 1024) ((short*)A2_s)[i] = 0;  // kg 0..24
  for (int i = tid; i < 3 * 16 * 8; i += 1024) {  // A2 kg25..27 zero + bias-one
    int jj = i & 7, gl = i >> 7;
    ((short*)&A2_s[25][0][0])[i] = (short)((gl == 0 && jj == 0) ? f2bf(1.f) : 0);
  }
  for (int i = tid; i < 3 * D1; i += 1024) fcw_s[i] = fc_w[i];
  if (tid < 3) fcb_s[tid] = fc_b[tid];

  const bool busy = (w < 7);                 // waves 0..6 own tiles 4w..4w+3
  const int m = l16 & 3, g16 = l16 >> 2;
  const int myMt = w * 4 + g16;
  const int jme = myMt * 4 + q;              // my element's j (>=100 invalid)
  const bool evalid = busy && (myMt < NT);
  int mts[4]; bool tv[4];
  bf16x8 wf[4][4];
  if (busy) {
#pragma unroll
    for (int i = 0; i < 4; ++i) {
      int mt = w * 4 + i; mts[i] = mt; tv[i] = (mt < NT);
#pragma unroll
      for (int kt = 0; kt < 4; ++kt)
        wf[i][kt] = *(const bf16x8*)(pk_hh + ((size_t)(kt * 4 + q) * NP + mt * 16 + l16) * 8);
    }
  }
  float c = 0.f;
  // per-lane own-element xg, running pointer (+102400 uint2 per t);
  // invalid jme (<=111) reads <=96B past the row — lands in ws, unused.
  const uint2* xgp = xg2 + (size_t)(b0 + m) * 100 + jme;
  uint2 xgCur = {0, 0};
  if (busy) { xgCur = *xgp; xgp += Bsz * 100; }
  __syncthreads();

  int p = 0;
  for (int t = 0; t < Tt; ++t) {
    if (busy) {
      uint2 xgNxt = xgCur;
      if (t < Tt - 1) { xgNxt = *xgp; xgp += Bsz * 100; }
      bf16x8 hfrag[4];
      // [l16] read: cols 4..15 hold write-time duplicates of rows 0..3.
#pragma unroll
      for (int kt = 0; kt < 4; ++kt) hfrag[kt] = *(const bf16x8*)A_s[p][kt * 4 + q][l16];
      f32x4 acc[4];
#pragma unroll
      for (int i = 0; i < 4; ++i) {
        acc[i] = (f32x4){0.f, 0.f, 0.f, 0.f};
        if (!tv[i]) continue;
#pragma unroll
        for (int kt = 0; kt < 4; ++kt)
          acc[i] = __builtin_amdgcn_mfma_f32_16x16x32_bf16(wf[i][kt], hfrag[kt], acc[i], 0, 0, 0);
      }
      float2 x01 = __half22float2(*(const __half2*)&xgCur.x);
      float2 x23 = __half22float2(*(const __half2*)&xgCur.y);
      float xr[4] = {x01.x, x01.y, x23.x, x23.y};
      float gr[4];
#pragma unroll
      for (int r = 0; r < 4; ++r) {
        float lo = (g16 & 1) ? acc[1][r] : acc[0][r];
        float hi = (g16 & 1) ? acc[3][r] : acc[2][r];
        gr[r] = ((g16 & 2) ? hi : lo) + xr[r];
      }
      float cc = sigm(gr[1]) * c + sigm(gr[0]) * tanhf_(gr[2]);
      c = cc;
      float h = sigm(gr[3]) * tanhf_(cc);
      if (evalid) {  // write-dup into all 4 mirror columns
        short hh = (short)f2bf(h);
        A_s[1 - p][jme >> 3][m][jme & 7] = hh;
        A_s[1 - p][jme >> 3][m + 4][jme & 7] = hh;
        A_s[1 - p][jme >> 3][m + 8][jme & 7] = hh;
        A_s[1 - p][jme >> 3][m + 12][jme & 7] = hh;
        if (t == Tt - 1) hf_s[m][jme] = h;
      }
      xgCur = xgNxt;
    }
    __syncthreads();
    p ^= 1;
  }

  // ---- layer-1 backward single step at t=T-1 (h=c=0) ----
  {
    const size_t base = ((size_t)(Tt - 1) * Bsz + b0) * H;
    if (tid < 100) {  // stage rows m=0..3 only (this block's batch)
      int m2 = tid / 25, j0 = (tid - (tid / 25) * 25) * 4;
      *(uint2*)&A2_s[j0 >> 3][m2][j0 & 7] = *(const uint2*)(h0fT + base + m2 * H + j0);
      int k = 100 + j0;
      *(uint2*)&A2_s[k >> 3][m2][k & 7] = *(const uint2*)(h0bT + base + m2 * H + j0);
    }
  }
  __syncthreads();
  if (busy) {
    f32x4 acc[4];
#pragma unroll
    for (int i = 0; i < 4; ++i) acc[i] = (f32x4){0.f, 0.f, 0.f, 0.f};
#pragma unroll
    for (int kt = 0; kt < 7; ++kt) {
      bf16x8 hf = *(const bf16x8*)A2_s[kt * 4 + q][l16 & 3];  // one-shot dup-read
#pragma unroll
      for (int i = 0; i < 4; ++i) {
        if (!tv[i]) continue;
        bf16x8 wfb = *(const bf16x8*)(pk1b + ((size_t)(kt * 4 + q) * NP + mts[i] * 16 + l16) * 8);
        acc[i] = __builtin_amdgcn_mfma_f32_16x16x32_bf16(wfb, hf, acc[i], 0, 0, 0);
      }
    }
    float gr[4];
#pragma unroll
    for (int r = 0; r < 4; ++r) {
      float lo = (g16 & 1) ? acc[1][r] : acc[0][r];
      float hi = (g16 & 1) ? acc[3][r] : acc[2][r];
      gr[r] = (g16 & 2) ? hi : lo;
    }
    float cc = sigm(gr[0]) * tanhf_(gr[2]);   // c_prev = 0
    if (evalid) hb_s[m][jme] = sigm(gr[3]) * tanhf_(cc);
  }
  __syncthreads();

  // ---- FC (3x200) + softmax ----
  if (tid < MB1 * 3) {
    int mr = tid / 3, cls = tid - mr * 3;
    float s = fcb_s[cls];
    for (int jj = 0; jj < H; ++jj) s += fcw_s[cls * D1 + jj] * hf_s[mr][jj];
    for (int jj = 0; jj < H; ++jj) s += fcw_s[cls * D1 + H + jj] * hb_s[mr][jj];
    logit_s[mr][cls] = s;
  }
  __syncthreads();
  if (tid < MB1) {
    float a = logit_s[tid][0], b = logit_s[tid][1], cc = logit_s[tid][2];
    float mx = fmaxf(a, fmaxf(b, cc));
    float e0 = __expf(a - mx), e1 = __expf(b - mx), e2 = __expf(cc - mx);
    float inv = 1.f / (e0 + e1 + e2);
    out[(b0 + tid) * 3 + 0] = e0 * inv;
    out[(b0 + tid) * 3 + 1] = e1 * inv;
    out[(b0 + tid) * 3 + 2] = e2 * inv;
  }
}

extern "C" void kernel_launch(void* const* d_in, const int* in_sizes, int n_in,
                              void* d_out, int out_size, void* d_ws, size_t ws_size,
                              hipStream_t stream) {
  const float* x        = (const float*)d_in[0];
  const float* w_ih_l0f = (const float*)d_in[1];
  const float* w_hh_l0f = (const float*)d_in[2];
  const float* b_ih_l0f = (const float*)d_in[3];
  const float* b_hh_l0f = (const float*)d_in[4];
  const float* w_ih_l0b = (const float*)d_in[5];
  const float* w_hh_l0b = (const float*)d_in[6];
  const float* b_ih_l0b = (const float*)d_in[7];
  const float* b_hh_l0b = (const float*)d_in[8];
  const float* w_ih_l1f = (const float*)d_in[9];
  const float* w_hh_l1f = (const float*)d_in[10];
  const float* b_ih_l1f = (const float*)d_in[11];
  const float* b_hh_l1f = (const float*)d_in[12];
  const float* w_ih_l1b = (const float*)d_in[13];
  // d_in[14] = w_hh_l1b unused (reverse dir at t=T-1 has h=0)
  const float* b_ih_l1b = (const float*)d_in[15];
  const float* b_hh_l1b = (const float*)d_in[16];
  const float* fc_w     = (const float*)d_in[17];
  const float* fc_b     = (const float*)d_in[18];

  unsigned short* h0fT = (unsigned short*)d_ws;
  unsigned short* h0bT = h0fT + (size_t)Tt * Bsz * H;
  __half* xgT          = (__half*)(h0bT + (size_t)Tt * Bsz * H);
  unsigned short* pk0f = (unsigned short*)(xgT + (size_t)Tt * Bsz * G);
  unsigned short* pk0b = pk0f + 16 * NP * 8;
  unsigned short* pkhh = pk0b + 16 * NP * 8;
  unsigned short* pkxg = pkhh + 16 * NP * 8;
  unsigned short* pk1b = pkxg + 28 * NP * 8;

  pack_all<<<dim3(448, 5), 256, 0, stream>>>(
      w_hh_l0f, w_ih_l0f, b_ih_l0f, b_hh_l0f,
      w_hh_l0b, w_ih_l0b, b_ih_l0b, b_hh_l0b,
      w_hh_l1f, b_ih_l1f, b_hh_l1f,
      w_ih_l1f, w_ih_l1b, b_ih_l1b, b_hh_l1b,
      pk0f, pk0b, pkhh, pkxg, pk1b);

  lstm_l0<<<dim3(Bsz / MB, 2), 1024, 0, stream>>>(x, pk0f, pk0b, h0fT, h0bT);
  gemm_xg<<<GSTRIDE, 1024, 0, stream>>>(h0fT, h0bT, pkxg, xgT);
  lstm_l1<<<Bsz / MB1, 1024, 0, stream>>>(h0fT, h0bT, pkhh, pk1b, xgT,
                                          fc_w, fc_b, (float*)d_out);
}